// Round 6
// baseline (433.181 us; speedup 1.0000x reference)
//
#include <hip/hip_runtime.h>
#include <hip/hip_bf16.h>

#define TT 4096
#define EE 512

typedef short short8 __attribute__((ext_vector_type(8)));
typedef float f32x4 __attribute__((ext_vector_type(4)));

__device__ __forceinline__ short f2bf(float f) {
    union { float f; unsigned u; } v; v.f = f;
    unsigned r = v.u + 0x7fffu + ((v.u >> 16) & 1u);
    return (short)(r >> 16);
}
__device__ __forceinline__ unsigned pk2bf(float lo, float hi) {
    __hip_bfloat162 h = __float22bfloat162_rn(make_float2(lo, hi));
    union { __hip_bfloat162 h; unsigned u; } c; c.h = h;
    return c.u;
}

// ws layout (bytes)
#define WS_WVT   0           // bf16 [128][544]  : Wv^T cols 0..511, M^T cols 512..542, col 543=0
#define WS_QBIAS 139264      // f32 [32][128]    : query@Wq + bv + att_b
#define WS_NV    155648      // f32 [128]        : normalized att_v
#define WS_P     156160      // f32 [32][4096]   : sigmoid probabilities
#define WS_PART  680448      // f32 [32][8][512] : attn_c partials

// ---------------------------------------------------------------- prep
__global__ void prep_kernel(const float* __restrict__ Wv, const float* __restrict__ conv_k,
                            const float* __restrict__ Wl, const float* __restrict__ query,
                            const float* __restrict__ Wq, const float* __restrict__ bv,
                            const float* __restrict__ att_b, const float* __restrict__ att_v,
                            const float* __restrict__ att_g,
                            short* __restrict__ wvt, float* __restrict__ q_bias,
                            float* __restrict__ nv) {
    if (blockIdx.x < 272) {
        int idx = blockIdx.x * 256 + threadIdx.x;   // 0..69631  (128*544)
        int a = idx / 544, k = idx % 544;
        float val = 0.f;
        if (k < 512) {
            val = Wv[k * 128 + a];
        } else if (k < 543) {
            int kk = k - 512;
            float s = 0.f;
            #pragma unroll
            for (int c = 0; c < 32; ++c) s += conv_k[kk * 32 + c] * Wl[c * 128 + a];
            val = s;
        }
        wvt[a * 544 + k] = f2bf(val);
    } else {
        __shared__ float tmp[2][128];
        int b = blockIdx.x - 272;
        int a = threadIdx.x & 127, h = threadIdx.x >> 7;
        const float* q = query + b * 512 + h * 256;
        const float* wq = Wq + (h * 256) * 128 + a;
        float s = 0.f;
        #pragma unroll 4
        for (int d = 0; d < 256; ++d) s += q[d] * wq[d * 128];
        tmp[h][a] = s;
        __syncthreads();
        if (threadIdx.x < 128) {
            q_bias[b * 128 + a] = tmp[0][a] + tmp[1][a] + bv[a] + att_b[a];
            if (b == 0) {
                float ss = 0.f;
                #pragma unroll
                for (int i = 0; i < 128; ++i) { float t = att_v[i]; ss += t * t; }
                nv[a] = att_g[0] * att_v[a] * rsqrtf(ss);
            }
        }
    }
}

// ---------------------------------------------------------------- energy GEMM
// 128x128 tile/block, 4 waves in 2x2 (each 64 rows x 64 cols -> 4x4 MFMA frags).
// Square tiling: 8 ds_read_b128 per thread-chunk (vs 18 in row-strip tiling).
// One barrier per K-chunk: iter kc writes buf[(kc+1)&1] (sealed by prev barrier),
// computes buf[kc&1]; named register sets S0/S1, peeled tail (no dyn reg idx).
__global__ __launch_bounds__(256, 3) void energy_kernel(
    const float* __restrict__ value, const int* __restrict__ vlen,
    const float* __restrict__ accum, const short* __restrict__ wvt,
    const float* __restrict__ q_bias, const float* __restrict__ nv,
    const float* __restrict__ score_bias, float* __restrict__ p_buf) {

    __shared__ __align__(16) short As[2][128 * 40];   // stride 40 shorts (2-way reads: free)
    __shared__ __align__(16) short Bs[2][128 * 40];
    __shared__ float esum[128][2];

    int bid = blockIdx.x;
    int b  = bid >> 5;             // 32 row-tiles per batch (T/128)
    int t0 = (bid & 31) << 7;
    int tid = threadIdx.x;
    int w = tid >> 6, l = tid & 63;
    int wr = w >> 1, wc = w & 1;   // 2x2 wave grid
    int l15 = l & 15, g = l >> 4;

    int len = vlen[b];
    if (t0 >= len) {               // fully-masked tile
        if (tid < 128) p_buf[b * TT + t0 + tid] = 0.f;
        return;
    }

    // staging geometry: A = 128 rows x 32 k fp32 (4 float4-granules/thread)
    int arw[4], agr[4];
    const float* abase[4];
    #pragma unroll
    for (int i = 0; i < 4; ++i) {
        int fl = tid + 256 * i;
        arw[i] = fl >> 3; agr[i] = fl & 7;
        abase[i] = value + ((size_t)(b * TT + t0 + arw[i])) * EE + agr[i] * 4;
    }
    int ba = tid >> 1, bh = (tid & 1) * 16;   // B = 128 a x 32 k bf16 (32B/thread)
    const short* bbase = wvt + ba * 544 + bh;

    f32x4 acc[4][4];
    #pragma unroll
    for (int i = 0; i < 4; ++i)
        #pragma unroll
        for (int j = 0; j < 4; ++j) acc[i][j] = (f32x4){0.f, 0.f, 0.f, 0.f};

#define LOAD_A(dst, kc) { _Pragma("unroll") \
    for (int i = 0; i < 4; ++i) dst[i] = *(const float4*)(abase[i] + (kc) * 32); }
#define LOAD_B(d0, d1, kc) { d0 = *(const short8*)(bbase + (kc) * 32); \
                             d1 = *(const short8*)(bbase + (kc) * 32 + 8); }
#define WRITE_BUF(bf_, av, b0, b1) { _Pragma("unroll") \
    for (int i = 0; i < 4; ++i) { uint2 pk; \
        pk.x = pk2bf(av[i].x, av[i].y); pk.y = pk2bf(av[i].z, av[i].w); \
        *(uint2*)(&As[bf_][arw[i] * 40 + agr[i] * 4]) = pk; } \
    *(short8*)(&Bs[bf_][ba * 40 + bh])     = b0; \
    *(short8*)(&Bs[bf_][ba * 40 + bh + 8]) = b1; }
#define COMPUTE(bf_) { short8 af[4], bq[4]; _Pragma("unroll") \
    for (int rt = 0; rt < 4; ++rt) \
        af[rt] = *(const short8*)(&As[bf_][(wr * 64 + rt * 16 + l15) * 40 + g * 8]); \
    _Pragma("unroll") \
    for (int ct = 0; ct < 4; ++ct) \
        bq[ct] = *(const short8*)(&Bs[bf_][(wc * 64 + ct * 16 + l15) * 40 + g * 8]); \
    _Pragma("unroll") \
    for (int rt = 0; rt < 4; ++rt) \
        _Pragma("unroll") \
        for (int ct = 0; ct < 4; ++ct) \
            acc[rt][ct] = __builtin_amdgcn_mfma_f32_16x16x32_bf16(af[rt], bq[ct], acc[rt][ct], 0, 0, 0); }

    float4 avA[4], avB[4];
    short8 bvA0, bvA1, bvB0, bvB1;

    // prologue: chunk 0 -> buf0; chunk 1 -> S1 regs
    LOAD_A(avA, 0); LOAD_B(bvA0, bvA1, 0);
    WRITE_BUF(0, avA, bvA0, bvA1);
    LOAD_A(avB, 1); LOAD_B(bvB0, bvB1, 1);
    __syncthreads();

    for (int it = 0; it < 7; ++it) {
        WRITE_BUF(1, avB, bvB0, bvB1);                      // chunk 2it+1
        LOAD_A(avA, 2 * it + 2); LOAD_B(bvA0, bvA1, 2 * it + 2);
        COMPUTE(0);                                          // chunk 2it
        __syncthreads();
        WRITE_BUF(0, avA, bvA0, bvA1);                      // chunk 2it+2
        LOAD_A(avB, 2 * it + 3); LOAD_B(bvB0, bvB1, 2 * it + 3);
        COMPUTE(1);                                          // chunk 2it+1
        __syncthreads();
    }
    WRITE_BUF(1, avB, bvB0, bvB1);                          // chunk 15
    COMPUTE(0);                                              // chunk 14
    __syncthreads();
    COMPUTE(1);                                              // chunk 15

    // band chunk (location conv as K-chunk 16): register A, L2-hot B cols 512..543
    {
        short8 bq[4];
        #pragma unroll
        for (int ct = 0; ct < 4; ++ct)
            bq[ct] = *(const short8*)(wvt + (wc * 64 + ct * 16 + l15) * 544 + 512 + g * 8);
        #pragma unroll
        for (int rt = 0; rt < 4; ++rt) {
            int row = t0 + wr * 64 + rt * 16 + l15;
            short8 af;
            #pragma unroll
            for (int i = 0; i < 8; ++i) {
                int kk = g * 8 + i;
                int t = row - 15 + kk;
                float v = (kk < 31 && t >= 0 && t < TT) ? accum[b * TT + t] : 0.f;
                af[i] = f2bf(v);
            }
            #pragma unroll
            for (int ct = 0; ct < 4; ++ct)
                acc[rt][ct] = __builtin_amdgcn_mfma_f32_16x16x32_bf16(af, bq[ct], acc[rt][ct], 0, 0, 0);
        }
    }

    // epilogue: per-wave partial energy over its 64 cols, cross-wave combine in LDS
    float qb[4], nvv[4];
    #pragma unroll
    for (int ct = 0; ct < 4; ++ct) {
        int a = wc * 64 + ct * 16 + l15;
        qb[ct]  = q_bias[b * 128 + a];
        nvv[ct] = nv[a];
    }
    __syncthreads();   // all buf reads done; esum region now safe to fill
    #pragma unroll
    for (int rt = 0; rt < 4; ++rt) {
        #pragma unroll
        for (int j = 0; j < 4; ++j) {
            float e = 0.f;
            #pragma unroll
            for (int ct = 0; ct < 4; ++ct)
                e += tanhf(acc[rt][ct][j] + qb[ct]) * nvv[ct];
            e += __shfl_xor(e, 1);
            e += __shfl_xor(e, 2);
            e += __shfl_xor(e, 4);
            e += __shfl_xor(e, 8);
            if (l15 == 0) esum[wr * 64 + rt * 16 + g * 4 + j][wc] = e;
        }
    }
    __syncthreads();
    if (tid < 128) {
        int t = t0 + tid;
        float p = 0.f;
        if (t < len) {
            float ee = esum[tid][0] + esum[tid][1] + score_bias[0];
            p = 1.f / (1.f + expf(-ee));
        }
        p_buf[b * TT + t] = p;
    }
#undef LOAD_A
#undef LOAD_B
#undef WRITE_BUF
#undef COMPUTE
}

// ---------------------------------------------------------------- fused weight + context partials
__global__ __launch_bounds__(256) void ctx_fused(const float* __restrict__ value,
                                                 const float* __restrict__ p_buf,
                                                 const float* __restrict__ prev,
                                                 float* __restrict__ outw,
                                                 float* __restrict__ part) {
    __shared__ float wsm[512];
    __shared__ int flags[8];
    int b = blockIdx.x, tc = blockIdx.y;
    int tid = threadIdx.x;
    if (tid < 8) flags[tid] = 0;
    __syncthreads();

    int tl = tid * 2;
    {
        int t = tc * 512 + tl;
        int gi = b * TT + t;
        float w0 = prev[gi] * p_buf[gi];
        if (t > 0) w0 += prev[gi - 1] * (1.f - p_buf[gi - 1]);
        float w1 = prev[gi + 1] * p_buf[gi + 1] + prev[gi] * (1.f - p_buf[gi]);
        outw[gi] = w0; outw[gi + 1] = w1;
        wsm[tl] = w0; wsm[tl + 1] = w1;
        if (w0 != 0.f) flags[tl >> 6] = 1;
        if (w1 != 0.f) flags[(tl + 1) >> 6] = 1;
    }
    __syncthreads();

    float ax = 0.f, ay = 0.f;
    const float* vbase = value + ((size_t)b * TT + tc * 512) * EE + tid * 2;
    for (int c = 0; c < 8; ++c) {
        if (flags[c]) {
            #pragma unroll 4
            for (int tt = c * 64; tt < c * 64 + 64; ++tt) {
                float wv = wsm[tt];
                if (wv != 0.f) {
                    float2 v = *(const float2*)(vbase + (size_t)tt * EE);
                    ax += wv * v.x; ay += wv * v.y;
                }
            }
        }
    }
    float2 r; r.x = ax; r.y = ay;
    *(float2*)(part + ((b * 8 + tc) * 512) + tid * 2) = r;
}

// ---------------------------------------------------------------- attn_c reduce
__global__ void ctx_reduce(const float* __restrict__ part, float* __restrict__ outc) {
    int idx = blockIdx.x * 256 + threadIdx.x;  // 0..16383
    int b = idx >> 9, e = idx & 511;
    float s = 0.f;
    #pragma unroll
    for (int tc = 0; tc < 8; ++tc) s += part[(b * 8 + tc) * 512 + e];
    outc[idx] = s;
}

// ---------------------------------------------------------------- launch
extern "C" void kernel_launch(void* const* d_in, const int* in_sizes, int n_in,
                              void* d_out, int out_size, void* d_ws, size_t ws_size,
                              hipStream_t stream) {
    const float* value  = (const float*)d_in[0];
    const int*   vlen   = (const int*)  d_in[1];
    const float* query  = (const float*)d_in[2];
    const float* accum  = (const float*)d_in[3];
    const float* prev   = (const float*)d_in[4];
    const float* Wv     = (const float*)d_in[5];
    const float* bv     = (const float*)d_in[6];
    const float* Wq     = (const float*)d_in[7];
    const float* conv_k = (const float*)d_in[8];
    const float* Wl     = (const float*)d_in[9];
    const float* att_v  = (const float*)d_in[10];
    const float* att_g  = (const float*)d_in[11];
    const float* att_b  = (const float*)d_in[12];
    const float* sbias  = (const float*)d_in[13];

    char* wsb = (char*)d_ws;
    short* wvt   = (short*)(wsb + WS_WVT);
    float* qbias = (float*)(wsb + WS_QBIAS);
    float* nv    = (float*)(wsb + WS_NV);
    float* pbuf  = (float*)(wsb + WS_P);
    float* part  = (float*)(wsb + WS_PART);

    float* outc = (float*)d_out;             // [32,512]
    float* outw = (float*)d_out + 32 * 512;  // [32,4096]

    prep_kernel<<<304, 256, 0, stream>>>(Wv, conv_k, Wl, query, Wq, bv, att_b,
                                         att_v, att_g, wvt, qbias, nv);
    energy_kernel<<<1024, 256, 0, stream>>>(value, vlen, accum, wvt, qbias, nv, sbias, pbuf);
    ctx_fused<<<dim3(32, 8), 256, 0, stream>>>(value, pbuf, prev, outw, part);
    ctx_reduce <<<64, 256, 0, stream>>>(part, outc);
}